// Round 3
// baseline (27.510 us; speedup 1.0000x reference)
//
#include <hip/hip_runtime.h>

// CenterLoss — R11: structural change — WAVE-PER-ROW, zero barriers, zero LDS.
// Theory: R8/R10's block-lockstep (2 __syncthreads per row across 4 waves)
// creates coherent load-drain windows across the 8 blocks/CU -> bursty memory
// idle; row kernel ran ~4.9 TB/s vs ~7 TB/s the fill kernels sustain.
// Now each wave owns one row: per-lane chunk-granular argmax (6 VALU/chunk),
// winning chunk re-loaded once (1KB/row, L2-hot) to recover the element index,
// one 6-step (max,min-idx) butterfly. Waves drift freely; 4096 independent
// waves = 16/CU, MLP~3 per wave => ~50KB in flight/CU >> ~9KB needed for peak.
// Kept (measured): two-kernel store-and-reduce (same-address atomics +45 us,
// acq-rel +165 us); f/c gather stays in the per-row tail (R9: hoisting it
// cost VGPRs and regressed).
//
// loss = mean_n( clip(||f||^2 + ||c_lab||^2 - 2 f.c_lab, 1e-12, 1e12) ) + (C-1)*1e-12
// lab = argmax_c predicts[n, c]  (first occurrence on ties).

#define NC   6625
#define FD   96
#define NROW 4096

__global__ __launch_bounds__(256) void centerloss_row_kernel(
    const float* __restrict__ features,
    const float* __restrict__ predicts,
    const float* __restrict__ centers,
    float* __restrict__ row_out)
{
    const int t = threadIdx.x;
    const int w = t >> 6;          // wave id in block: 0..3
    const int l = t & 63;          // lane
    const int n = blockIdx.x * 4 + w;   // one row per wave
    const float NEG_INF = -__builtin_huge_valf();

    const size_t base = (size_t)n * NC;
    const float* row = predicts + base;

    // Row start is only 4B-aligned (6625 % 4 == 1): scalar prologue to 16B.
    const int pro  = (int)((4 - (base & 3)) & 3);     // 0..3
    const int nvec = (NC - pro) >> 2;                 // 1655 or 1656
    const float4* vrow = (const float4*)(row + pro);

    // Lane l covers vec indices l + 64k, k = 0..25.
    // k <= 24: max idx 63 + 1536 = 1599 < 1655 -> always valid.
    // k == 25: valid iff l + 1600 < nvec (~55-56 lanes).
    // Pre-issue the irregular loads so their latency hides under the stream.
    float vpro = NEG_INF;
    if (l < pro) vpro = row[l];                       // idx = l (smallest)
    const int tailStart = pro + 4 * nvec;
    float vtail = NEG_INF;
    if (l < NC - tailStart) vtail = row[tailStart + l];  // idx (largest)
    float4 v25 = make_float4(NEG_INF, NEG_INF, NEG_INF, NEG_INF);
    if (l + 1600 < nvec) v25 = vrow[l + 1600];

    // Chunk-granular argmax: track (m, kc). Strict > keeps earliest chunk.
    // Codes: -1 = prologue, 0..25 = chunks, 26 = tail.
    float m = vpro;                                    // -inf if no prologue lane
    int   kc = -1;

    const float4* p = vrow + l;
    float4 cur = p[0];                                 // chunk 0

    // Hand-unrolled x2, runtime k (#pragma unroll 1): keeps MLP ~3 without
    // letting the compiler hoist all 26 chunk loads into live registers.
    #pragma unroll 1
    for (int k = 0; k < 24; k += 2) {
        const float4 n0 = p[64];                       // chunk k+1
        const float4 n1 = p[128];                      // chunk k+2 (<= 24)
        p += 128;
        float m4 = fmaxf(fmaxf(cur.x, cur.y), fmaxf(cur.z, cur.w));
        if (m4 > m) { m = m4; kc = k; }
        m4 = fmaxf(fmaxf(n0.x, n0.y), fmaxf(n0.z, n0.w));
        if (m4 > m) { m = m4; kc = k + 1; }
        cur = n1;
    }
    // chunk 24 (in cur), fully valid
    {
        const float m4 = fmaxf(fmaxf(cur.x, cur.y), fmaxf(cur.z, cur.w));
        if (m4 > m) { m = m4; kc = 24; }
    }
    // chunk 25 (predicated, invalid lanes saw -inf)
    {
        const float m4 = fmaxf(fmaxf(v25.x, v25.y), fmaxf(v25.z, v25.w));
        if (m4 > m) { m = m4; kc = 25; }
    }
    // tail (largest indices, so strict > keeps any earlier equal max)
    if (vtail > m) { m = vtail; kc = 26; }

    // Reconstruct this lane's first index equal to its max m.
    int fi;
    if (kc == -1)      fi = l;
    else if (kc == 26) fi = tailStart + l;
    else {
        // Re-load winning chunk (just streamed -> L2-hot). First matching
        // component = first occurrence within the chunk.
        const float4 v = vrow[l + 64 * kc];
        const int j = (v.x == m) ? 0 : ((v.y == m) ? 1 : ((v.z == m) ? 2 : 3));
        fi = pro + 4 * (l + 64 * kc) + j;
    }

    // Wave-64 (max, min-index) butterfly -> uniform (M, lab) on all lanes.
    #pragma unroll
    for (int off = 32; off > 0; off >>= 1) {
        const float m2 = __shfl_xor(m, off);
        const int   f2 = __shfl_xor(fi, off);
        const bool take = (m2 > m) || (m2 == m && f2 < fi);
        m  = take ? m2 : m;
        fi = take ? f2 : fi;
    }
    const int lab = fi;

    // ---- dist: lanes 0..23 load one float4 of f and c (rows 384B-aligned) ----
    float sf2 = 0.f, sc2 = 0.f, sfc = 0.f;
    if (l < 24) {   // 24 * float4 = 96 floats
        const float4* f4 = (const float4*)(features + (size_t)n   * FD);
        const float4* c4 = (const float4*)(centers  + (size_t)lab * FD);
        const float4 f = f4[l], c = c4[l];
        sf2 = f.x*f.x + f.y*f.y + f.z*f.z + f.w*f.w;
        sc2 = c.x*c.x + c.y*c.y + c.z*c.z + c.w*c.w;
        sfc = f.x*c.x + f.y*c.y + f.z*c.z + f.w*c.w;
    }
    #pragma unroll
    for (int off = 16; off > 0; off >>= 1) {   // xor<32 stays within 0..31
        sf2 += __shfl_xor(sf2, off);
        sc2 += __shfl_xor(sc2, off);
        sfc += __shfl_xor(sfc, off);
    }
    if (l == 0) {
        float dist = sf2 + sc2 - 2.0f * sfc;
        dist = fminf(fmaxf(dist, 1e-12f), 1e12f);
        row_out[n] = dist;
    }
}

// Deterministic final reduce (single block, fixed order -> bit-identical replays).
__global__ __launch_bounds__(256) void centerloss_reduce_kernel(
    const float* __restrict__ row_out,
    float* __restrict__ out)
{
    const int t = threadIdx.x;
    const float4* r4 = (const float4*)row_out;   // NROW/4 = 1024 float4s
    float s = 0.f;
    #pragma unroll
    for (int k = 0; k < NROW / 4 / 256; ++k) {
        float4 v = r4[t + 256 * k];
        s += v.x + v.y + v.z + v.w;
    }
    #pragma unroll
    for (int off = 32; off > 0; off >>= 1) s += __shfl_xor(s, off);

    __shared__ float sv[4];
    if ((t & 63) == 0) sv[t >> 6] = s;
    __syncthreads();
    if (t == 0)
        out[0] = (sv[0] + sv[1] + sv[2] + sv[3]) / (float)NROW
                 + (float)(NC - 1) * 1e-12f;
}

extern "C" void kernel_launch(void* const* d_in, const int* in_sizes, int n_in,
                              void* d_out, int out_size, void* d_ws, size_t ws_size,
                              hipStream_t stream) {
    const float* features = (const float*)d_in[0];
    const float* predicts = (const float*)d_in[1];
    const float* centers  = (const float*)d_in[2];
    float* out = (float*)d_out;
    float* ws  = (float*)d_ws;   // NROW floats of per-row clipped distances

    centerloss_row_kernel<<<NROW / 4, 256, 0, stream>>>(features, predicts, centers, ws);
    centerloss_reduce_kernel<<<1, 256, 0, stream>>>(ws, out);
}

// Round 4
// 26.589 us; speedup vs baseline: 1.0347x; 1.0347x over previous
//
#include <hip/hip_runtime.h>

// CenterLoss — R12: R11's barrier-free wave-per-row skeleton + the fix for
// R11's measured defect: 8-DEEP load pipeline instead of 2-deep.
// R11 post-mortem: per-wave in-flight was ~2KB (wait fired same iteration as
// issue) -> 32KB/CU, at the starvation edge of Little's law with LOADED HBM
// latency (~2-3k cyc) -> regressed to 27.5us. R8's 7-deep burst (200KB/CU)
// beat it despite barriers. Fix: hand-unrolled 8-slot rotation — process the
// oldest chunk, immediately reissue slot with chunk k+8. 8KB/wave in flight
// through the whole 24-chunk steady state; 16 waves/CU -> 128KB/CU, no
// barrier ever drains the queue (zero __syncthreads, zero LDS).
// Occupancy is grid-limited (1024 blocks = 4 blocks/CU = 16 waves/CU), so
// VGPR headroom up to 128 — no cliff risk from the 8 live float4 slots.
// Kept (measured): two-kernel store-and-reduce (same-address atomics +45us,
// acq-rel +165us); R11's proven argmax semantics (chunk-granular strict->,
// L2-hot winning-chunk reload, (max,min-idx) butterfly) — absmax 0.
//
// loss = mean_n( clip(||f||^2 + ||c_lab||^2 - 2 f.c_lab, 1e-12, 1e12) ) + (C-1)*1e-12
// lab = argmax_c predicts[n, c]  (first occurrence on ties).

#define NC   6625
#define FD   96
#define NROW 4096

__global__ __launch_bounds__(256) void centerloss_row_kernel(
    const float* __restrict__ features,
    const float* __restrict__ predicts,
    const float* __restrict__ centers,
    float* __restrict__ row_out)
{
    const int t = threadIdx.x;
    const int w = t >> 6;          // wave id in block: 0..3
    const int l = t & 63;          // lane
    const int n = blockIdx.x * 4 + w;   // one row per wave
    const float NEG_INF = -__builtin_huge_valf();

    const size_t base = (size_t)n * NC;
    const float* row = predicts + base;

    // Row start is only 4B-aligned (6625 % 4 == 1): scalar prologue to 16B.
    const int pro  = (int)((4 - (base & 3)) & 3);     // 0..3
    const int nvec = (NC - pro) >> 2;                 // 1655 or 1656
    const float4* vrow = (const float4*)(row + pro);

    // Lane l covers vec indices l + 64k, k = 0..25.
    // k <= 24: max idx 63 + 1536 = 1599 < min nvec 1655 -> always valid.
    // k == 25: valid iff l + 1600 < nvec (~55-56 lanes).
    // Irregular loads issued first: oldest in queue, retire first, needed last.
    float vpro = NEG_INF;
    if (l < pro) vpro = row[l];                       // idx = l (smallest)
    const int tailStart = pro + 4 * nvec;
    float vtail = NEG_INF;
    if (l < NC - tailStart) vtail = row[tailStart + l];  // idx (largest)
    float4 v25 = make_float4(NEG_INF, NEG_INF, NEG_INF, NEG_INF);
    if (l + 1600 < nvec) v25 = vrow[l + 1600];
    const float4 v24 = vrow[l + 1536];                // chunk 24, always valid

    // ---- 8-deep pipeline over chunks 0..23 ----
    const float4* p = vrow + l;
    float4 a0 = p[0],   a1 = p[64],  a2 = p[128], a3 = p[192],
           a4 = p[256], a5 = p[320], a6 = p[384], a7 = p[448];

    // Chunk-granular argmax: (m, kc), strict > keeps earliest chunk.
    // Codes: -1 = prologue, 0..25 = chunks, 26 = tail.
    float m = vpro;
    int   kc = -1;

    #define PROC(A, K) { const float m4 = fmaxf(fmaxf((A).x, (A).y),          \
                                                fmaxf((A).z, (A).w));         \
                         if (m4 > m) { m = m4; kc = (K); } }

    // Steady state: process oldest chunk k, reissue its slot with chunk k+8.
    PROC(a0,  0) a0 = p[ 512];
    PROC(a1,  1) a1 = p[ 576];
    PROC(a2,  2) a2 = p[ 640];
    PROC(a3,  3) a3 = p[ 704];
    PROC(a4,  4) a4 = p[ 768];
    PROC(a5,  5) a5 = p[ 832];
    PROC(a6,  6) a6 = p[ 896];
    PROC(a7,  7) a7 = p[ 960];
    PROC(a0,  8) a0 = p[1024];
    PROC(a1,  9) a1 = p[1088];
    PROC(a2, 10) a2 = p[1152];
    PROC(a3, 11) a3 = p[1216];
    PROC(a4, 12) a4 = p[1280];
    PROC(a5, 13) a5 = p[1344];
    PROC(a6, 14) a6 = p[1408];
    PROC(a7, 15) a7 = p[1472];
    // Drain: chunks 16..23, then the pre-issued 24/25.
    PROC(a0, 16) PROC(a1, 17) PROC(a2, 18) PROC(a3, 19)
    PROC(a4, 20) PROC(a5, 21) PROC(a6, 22) PROC(a7, 23)
    PROC(v24, 24) PROC(v25, 25)
    #undef PROC
    // Tail has the largest indices: strict > keeps any earlier equal max.
    if (vtail > m) { m = vtail; kc = 26; }

    // Reconstruct this lane's first index equal to its max m.
    int fi;
    if (kc == -1)      fi = l;
    else if (kc == 26) fi = tailStart + l;
    else {
        // Re-load winning chunk (just streamed -> L2-hot). First matching
        // component = first occurrence within the chunk.
        const float4 v = vrow[l + 64 * kc];
        const int j = (v.x == m) ? 0 : ((v.y == m) ? 1 : ((v.z == m) ? 2 : 3));
        fi = pro + 4 * (l + 64 * kc) + j;
    }

    // Wave-64 (max, min-index) butterfly -> uniform (M, lab) on all lanes.
    #pragma unroll
    for (int off = 32; off > 0; off >>= 1) {
        const float m2 = __shfl_xor(m, off);
        const int   f2 = __shfl_xor(fi, off);
        const bool take = (m2 > m) || (m2 == m && f2 < fi);
        m  = take ? m2 : m;
        fi = take ? f2 : fi;
    }
    const int lab = fi;

    // ---- dist: lanes 0..23 load one float4 of f and c (rows 384B-aligned) ----
    float sf2 = 0.f, sc2 = 0.f, sfc = 0.f;
    if (l < 24) {   // 24 * float4 = 96 floats
        const float4* f4 = (const float4*)(features + (size_t)n   * FD);
        const float4* c4 = (const float4*)(centers  + (size_t)lab * FD);
        const float4 f = f4[l], c = c4[l];
        sf2 = f.x*f.x + f.y*f.y + f.z*f.z + f.w*f.w;
        sc2 = c.x*c.x + c.y*c.y + c.z*c.z + c.w*c.w;
        sfc = f.x*c.x + f.y*c.y + f.z*c.z + f.w*c.w;
    }
    #pragma unroll
    for (int off = 16; off > 0; off >>= 1) {   // xor<32 stays within 0..31
        sf2 += __shfl_xor(sf2, off);
        sc2 += __shfl_xor(sc2, off);
        sfc += __shfl_xor(sfc, off);
    }
    if (l == 0) {
        float dist = sf2 + sc2 - 2.0f * sfc;
        dist = fminf(fmaxf(dist, 1e-12f), 1e12f);
        row_out[n] = dist;
    }
}

// Deterministic final reduce (single block, fixed order -> bit-identical replays).
__global__ __launch_bounds__(256) void centerloss_reduce_kernel(
    const float* __restrict__ row_out,
    float* __restrict__ out)
{
    const int t = threadIdx.x;
    const float4* r4 = (const float4*)row_out;   // NROW/4 = 1024 float4s
    float s = 0.f;
    #pragma unroll
    for (int k = 0; k < NROW / 4 / 256; ++k) {
        float4 v = r4[t + 256 * k];
        s += v.x + v.y + v.z + v.w;
    }
    #pragma unroll
    for (int off = 32; off > 0; off >>= 1) s += __shfl_xor(s, off);

    __shared__ float sv[4];
    if ((t & 63) == 0) sv[t >> 6] = s;
    __syncthreads();
    if (t == 0)
        out[0] = (sv[0] + sv[1] + sv[2] + sv[3]) / (float)NROW
                 + (float)(NC - 1) * 1e-12f;
}

extern "C" void kernel_launch(void* const* d_in, const int* in_sizes, int n_in,
                              void* d_out, int out_size, void* d_ws, size_t ws_size,
                              hipStream_t stream) {
    const float* features = (const float*)d_in[0];
    const float* predicts = (const float*)d_in[1];
    const float* centers  = (const float*)d_in[2];
    float* out = (float*)d_out;
    float* ws  = (float*)d_ws;   // NROW floats of per-row clipped distances

    centerloss_row_kernel<<<NROW / 4, 256, 0, stream>>>(features, predicts, centers, ws);
    centerloss_reduce_kernel<<<1, 256, 0, stream>>>(ws, out);
}